// Round 1
// baseline (278.605 us; speedup 1.0000x reference)
//
#include <hip/hip_runtime.h>

// ---------------------------------------------------------------------------
// SABlock fused pipeline for MI355X (gfx950)
//   x:[4,2048,512] f32 -> LN -> +pe -> QKV proj -> 8-head attn -> out proj -> +x
// Strategy: bf16 MFMA (16x16x32) for all matmul-shaped work, fp32 accum.
// ---------------------------------------------------------------------------

typedef __bf16 bf16;
typedef __bf16 bf16x2 __attribute__((ext_vector_type(2)));
typedef __bf16 bf16x4 __attribute__((ext_vector_type(4)));
typedef __bf16 bf16x8 __attribute__((ext_vector_type(8)));
typedef float  f32x4  __attribute__((ext_vector_type(4)));

#define MFMA16(a, b, c) __builtin_amdgcn_mfma_f32_16x16x32_bf16((a), (b), (c), 0, 0, 0)

__device__ __forceinline__ void gload16(const void* g, void* l) {
  // async global->LDS, 16B per lane; LDS dest is wave-uniform base + lane*16
  __builtin_amdgcn_global_load_lds(
      (const __attribute__((address_space(1))) unsigned int*)g,
      (__attribute__((address_space(3))) unsigned int*)l, 16, 0, 0);
}

// ---------------------------------------------------------------------------
// Weight transpose to bf16: dst[o][i] = (bf16)src[i][o], 512x512 each.
// z = 0,1,2 -> wq,wk,wv into wqkvT (rows 0-511,512-1023,1024-1535); z=3 -> woT
// ---------------------------------------------------------------------------
__global__ void wtrans_kernel(const float* __restrict__ wq, const float* __restrict__ wk,
                              const float* __restrict__ wv, const float* __restrict__ wo,
                              bf16* __restrict__ wqkvT, bf16* __restrict__ woT) {
  __shared__ float tile[32][33];
  int z = blockIdx.z;
  const float* src = (z == 0) ? wq : (z == 1) ? wk : (z == 2) ? wv : wo;
  bf16* dst = (z < 3) ? (wqkvT + (size_t)z * 512 * 512) : woT;
  int bx = blockIdx.x, by = blockIdx.y;   // bx: out-dim tile, by: in-dim tile
  int tx = threadIdx.x, ty = threadIdx.y;
#pragma unroll
  for (int yy = 0; yy < 4; ++yy)
    tile[ty + 8 * yy][tx] = src[(size_t)(by * 32 + ty + 8 * yy) * 512 + bx * 32 + tx];
  __syncthreads();
#pragma unroll
  for (int yy = 0; yy < 4; ++yy)
    dst[(size_t)(bx * 32 + ty + 8 * yy) * 512 + by * 32 + tx] = (bf16)tile[tx][ty + 8 * yy];
}

// ---------------------------------------------------------------------------
// LayerNorm + positional embedding -> bf16 h [8192][512]
// ---------------------------------------------------------------------------
__global__ __launch_bounds__(256) void ln_pe_kernel(const float* __restrict__ x,
                                                    const float* __restrict__ w,
                                                    const float* __restrict__ b,
                                                    const float* __restrict__ pe,
                                                    bf16* __restrict__ h) {
  int row = blockIdx.x;
  int tid = threadIdx.x;
  const float2 xv = *(const float2*)(x + (size_t)row * 512 + tid * 2);
  float s = xv.x + xv.y;
  float ss = xv.x * xv.x + xv.y * xv.y;
#pragma unroll
  for (int off = 32; off; off >>= 1) {
    s += __shfl_xor(s, off);
    ss += __shfl_xor(ss, off);
  }
  __shared__ float ps[4], pss[4];
  int wave = tid >> 6;
  if ((tid & 63) == 0) { ps[wave] = s; pss[wave] = ss; }
  __syncthreads();
  s = ps[0] + ps[1] + ps[2] + ps[3];
  ss = pss[0] + pss[1] + pss[2] + pss[3];
  float mu = s * (1.0f / 512.0f);
  float var = ss * (1.0f / 512.0f) - mu * mu;
  float rs = rsqrtf(var + 1e-5f);
  int n = row & 2047;
  float2 wv2 = *(const float2*)(w + tid * 2);
  float2 bv2 = *(const float2*)(b + tid * 2);
  float2 pv2 = *(const float2*)(pe + (size_t)n * 512 + tid * 2);
  bf16x2 o;
  o[0] = (bf16)((xv.x - mu) * rs * wv2.x + bv2.x + pv2.x);
  o[1] = (bf16)((xv.y - mu) * rs * wv2.y + bv2.y + pv2.y);
  *(bf16x2*)(h + (size_t)row * 512 + tid * 2) = o;
}

// ---------------------------------------------------------------------------
// Shared GEMM mainloop: C[128x128] tile = A[128xK] * Bt[128xK]^T, K=512.
// A, Bt both row-major with row stride 512 bf16. m97 structure:
// global_load_lds width-16 staging, 2 barriers per K-step, 16x16x32 MFMA.
// 4 waves in 2x2; each wave computes 64x64 via 4x4 fragments.
// ---------------------------------------------------------------------------
__device__ __forceinline__ void gemm_tile(const bf16* __restrict__ A,
                                          const bf16* __restrict__ Bt,
                                          f32x4 acc[4][4]) {
  __shared__ uint4 lds[1024];  // 16 KiB: [0,8K) A-tile [128][32], [8K,16K) B-tile
  char* lA = (char*)lds;
  char* lB = (char*)(lds + 512);
  const int tid = threadIdx.x, wave = tid >> 6, lane = tid & 63;
  const int wrow = wave >> 1, wcol = wave & 1;
  const int l15 = lane & 15, lg = lane >> 4;
  const int tm = blockIdx.x, tn = blockIdx.y;
  const char* Ab = (const char*)A;
  const char* Bb = (const char*)Bt;
  const f32x4 z = {0.f, 0.f, 0.f, 0.f};
#pragma unroll
  for (int mi = 0; mi < 4; ++mi)
#pragma unroll
    for (int ni = 0; ni < 4; ++ni) acc[mi][ni] = z;

  for (int kt = 0; kt < 16; ++kt) {
#pragma unroll
    for (int issue = 0; issue < 2; ++issue) {
      int ob = issue * 4096 + wave * 1024;   // wave-uniform LDS byte base
      int ol = ob + lane * 16;               // this lane's byte slot
      int row = ol >> 6;                     // 64B per LDS row (32 bf16)
      int kb = ol & 63;
      gload16(Ab + (size_t)(tm * 128 + row) * 1024 + kt * 64 + kb, lA + ob);
      gload16(Bb + (size_t)(tn * 128 + row) * 1024 + kt * 64 + kb, lB + ob);
    }
    __syncthreads();  // drains vmcnt before barrier -> LDS tiles ready
    bf16x8 av[4], bv[4];
#pragma unroll
    for (int mi = 0; mi < 4; ++mi)
      av[mi] = *(const bf16x8*)(lA + (wrow * 64 + mi * 16 + l15) * 64 + lg * 16);
#pragma unroll
    for (int ni = 0; ni < 4; ++ni)
      bv[ni] = *(const bf16x8*)(lB + (wcol * 64 + ni * 16 + l15) * 64 + lg * 16);
#pragma unroll
    for (int mi = 0; mi < 4; ++mi)
#pragma unroll
      for (int ni = 0; ni < 4; ++ni)
        acc[mi][ni] = MFMA16(av[mi], bv[ni], acc[mi][ni]);
    __syncthreads();  // protect LDS before next stage
  }
}

// ---------------------------------------------------------------------------
// QKV projection GEMM. h[8192][512] x wqkvT[1536][512]^T.
// Epilogue: q (scaled 1/8) -> [bh][n][64]; k -> [bh][n][64]; v+bv -> [bh][64][n]
// ---------------------------------------------------------------------------
__global__ __launch_bounds__(256, 2) void gemm_qkv_kernel(
    const bf16* __restrict__ h, const bf16* __restrict__ wqkvT,
    const float* __restrict__ bvec, bf16* __restrict__ qo, bf16* __restrict__ ko,
    bf16* __restrict__ vo) {
  f32x4 acc[4][4];
  gemm_tile(h, wqkvT, acc);
  const int tid = threadIdx.x, wave = tid >> 6, lane = tid & 63;
  const int wrow = wave >> 1, wcol = wave & 1;
  const int l15 = lane & 15, lg = lane >> 4;
  const int row0 = blockIdx.x * 128 + wrow * 64;
  const int col0 = blockIdx.y * 128 + wcol * 64;
#pragma unroll
  for (int mi = 0; mi < 4; ++mi) {
#pragma unroll
    for (int ni = 0; ni < 4; ++ni) {
      int c = col0 + ni * 16 + l15;
      int proj = c >> 9;        // 0=q 1=k 2=v
      int wc = c & 511;
      int head = wc >> 6, d = wc & 63;
      int rb = row0 + mi * 16 + lg * 4;  // 4 consecutive rows, same batch
      int bb = rb >> 11, n = rb & 2047;
      if (proj == 2) {
        float bias = bvec[wc];
        bf16x4 pv;
#pragma unroll
        for (int reg = 0; reg < 4; ++reg) pv[reg] = (bf16)(acc[mi][ni][reg] + bias);
        *(bf16x4*)(vo + ((size_t)(bb * 8 + head) * 64 + d) * 2048 + n) = pv;
      } else if (proj == 0) {
#pragma unroll
        for (int reg = 0; reg < 4; ++reg)
          qo[((size_t)(bb * 8 + head) * 2048 + (n + reg)) * 64 + d] =
              (bf16)(acc[mi][ni][reg] * 0.125f);
      } else {
#pragma unroll
        for (int reg = 0; reg < 4; ++reg)
          ko[((size_t)(bb * 8 + head) * 2048 + (n + reg)) * 64 + d] =
              (bf16)acc[mi][ni][reg];
      }
    }
  }
}

// ---------------------------------------------------------------------------
// Flash attention. Grid (16 q-tiles, 32 bh). 256 threads = 4 waves;
// wave owns 32 q-rows (2 row-tiles of 16). KV tiles of 64 keys.
// LDS: K[64][64], Vt[64][64] (both XOR-swizzled), P per-wave [16][64].
// ---------------------------------------------------------------------------
__global__ __launch_bounds__(256, 2) void attn_kernel(const bf16* __restrict__ q,
                                                      const bf16* __restrict__ k,
                                                      const bf16* __restrict__ v,
                                                      bf16* __restrict__ ao) {
  __shared__ uint4 sK[512], sV[512], sP[512];  // 8 KiB each
  char* Ksh = (char*)sK;
  char* Vsh = (char*)sV;
  const int tid = threadIdx.x, wave = tid >> 6, lane = tid & 63;
  const int l15 = lane & 15, lg = lane >> 4;
  const int qt = blockIdx.x, bh = blockIdx.y;
  const int bb = bh >> 3, hh = bh & 7;

  // Q fragments in registers (A-operand layout), already scaled by 1/8
  const bf16* qbase = q + ((size_t)bh * 2048 + qt * 128 + wave * 32) * 64;
  bf16x8 qf[2][2];
#pragma unroll
  for (int mi = 0; mi < 2; ++mi)
#pragma unroll
    for (int dk = 0; dk < 2; ++dk)
      qf[mi][dk] = *(const bf16x8*)(qbase + (mi * 16 + l15) * 64 + dk * 32 + lg * 8);

  const f32x4 z = {0.f, 0.f, 0.f, 0.f};
  f32x4 oacc[2][4];
  float mrun[2][4], lrun[2][4];
#pragma unroll
  for (int mi = 0; mi < 2; ++mi) {
#pragma unroll
    for (int ds = 0; ds < 4; ++ds) oacc[mi][ds] = z;
#pragma unroll
    for (int r = 0; r < 4; ++r) { mrun[mi][r] = -__builtin_inff(); lrun[mi][r] = 0.f; }
  }

  const bf16* kb_ = k + (size_t)bh * 2048 * 64;
  const bf16* vb_ = v + (size_t)bh * 64 * 2048;
  char* Pw = (char*)sP + wave * 2048;

  uint4 kreg[2], vreg[2];
#pragma unroll
  for (int c = 0; c < 2; ++c) {  // prefetch tile 0
    int idx = tid + c * 256, r = idx >> 3, ch = idx & 7;
    kreg[c] = *(const uint4*)(kb_ + (size_t)r * 64 + ch * 8);
    vreg[c] = *(const uint4*)(vb_ + (size_t)r * 2048 + ch * 8);
  }

  for (int t = 0; t < 32; ++t) {
    __syncthreads();  // all waves done reading previous tile's LDS
#pragma unroll
    for (int c = 0; c < 2; ++c) {
      int idx = tid + c * 256, r = idx >> 3, ch = idx & 7;
      int swz = (r & 7) << 4;
      *(uint4*)(Ksh + ((r * 128 + ch * 16) ^ swz)) = kreg[c];
      *(uint4*)(Vsh + ((r * 128 + ch * 16) ^ swz)) = vreg[c];
    }
    __syncthreads();
    if (t + 1 < 32) {  // T14-lite: issue next-tile loads before MFMA phase
#pragma unroll
      for (int c = 0; c < 2; ++c) {
        int idx = tid + c * 256, r = idx >> 3, ch = idx & 7;
        kreg[c] = *(const uint4*)(kb_ + (size_t)((t + 1) * 64 + r) * 64 + ch * 8);
        vreg[c] = *(const uint4*)(vb_ + (size_t)r * 2048 + (t + 1) * 64 + ch * 8);
      }
    }
#pragma unroll
    for (int mi = 0; mi < 2; ++mi) {
      // S = Q K^T : 16 q-rows x 64 keys
      f32x4 sacc[4];
#pragma unroll
      for (int kt = 0; kt < 4; ++kt) sacc[kt] = z;
#pragma unroll
      for (int dk = 0; dk < 2; ++dk) {
#pragma unroll
        for (int kt = 0; kt < 4; ++kt) {
          int key = kt * 16 + l15;
          bf16x8 kf = *(const bf16x8*)(
              Ksh + ((key * 128 + (dk * 32 + lg * 8) * 2) ^ ((key & 7) << 4)));
          sacc[kt] = MFMA16(qf[mi][dk], kf, sacc[kt]);
        }
      }
      // online softmax (wave-parallel): row r = lg*4+reg, col = kt*16+l15
      float mt[4];
#pragma unroll
      for (int reg = 0; reg < 4; ++reg)
        mt[reg] = fmaxf(fmaxf(sacc[0][reg], sacc[1][reg]),
                        fmaxf(sacc[2][reg], sacc[3][reg]));
#pragma unroll
      for (int off = 1; off <= 8; off <<= 1)
#pragma unroll
        for (int reg = 0; reg < 4; ++reg)
          mt[reg] = fmaxf(mt[reg], __shfl_xor(mt[reg], off));
      float pr[4][4], rsum[4];
#pragma unroll
      for (int reg = 0; reg < 4; ++reg) {
        float mn = fmaxf(mrun[mi][reg], mt[reg]);
        float sc = __expf(mrun[mi][reg] - mn);  // -inf -> 0 on first tile
        mrun[mi][reg] = mn;
        lrun[mi][reg] *= sc;
#pragma unroll
        for (int ds = 0; ds < 4; ++ds) oacc[mi][ds][reg] *= sc;
        float s0 = 0.f;
#pragma unroll
        for (int kt = 0; kt < 4; ++kt) {
          float p = __expf(sacc[kt][reg] - mn);
          pr[kt][reg] = p;
          s0 += p;
        }
        rsum[reg] = s0;
      }
#pragma unroll
      for (int off = 1; off <= 8; off <<= 1)
#pragma unroll
        for (int reg = 0; reg < 4; ++reg) rsum[reg] += __shfl_xor(rsum[reg], off);
#pragma unroll
      for (int reg = 0; reg < 4; ++reg) lrun[mi][reg] += rsum[reg];
      // P -> LDS (bf16, swizzled), then PV MFMAs (same-wave DS ordering)
#pragma unroll
      for (int kt = 0; kt < 4; ++kt)
#pragma unroll
        for (int reg = 0; reg < 4; ++reg) {
          int row = lg * 4 + reg, col = kt * 16 + l15;
          *(bf16*)(Pw + ((row * 128 + col * 2) ^ ((row & 7) << 4))) =
              (bf16)pr[kt][reg];
        }
#pragma unroll
      for (int ks = 0; ks < 2; ++ks) {
        bf16x8 pf = *(const bf16x8*)(
            Pw + ((l15 * 128 + (ks * 32 + lg * 8) * 2) ^ ((l15 & 7) << 4)));
#pragma unroll
        for (int ds = 0; ds < 4; ++ds) {
          int dd = ds * 16 + l15;
          bf16x8 vf = *(const bf16x8*)(
              Vsh + ((dd * 128 + (ks * 32 + lg * 8) * 2) ^ ((dd & 7) << 4)));
          oacc[mi][ds] = MFMA16(pf, vf, oacc[mi][ds]);
        }
      }
    }
  }
  // epilogue: normalize and write ao[b][n][h*64+d] bf16
  const int qrow0 = qt * 128 + wave * 32;
#pragma unroll
  for (int mi = 0; mi < 2; ++mi)
#pragma unroll
    for (int ds = 0; ds < 4; ++ds)
#pragma unroll
      for (int reg = 0; reg < 4; ++reg) {
        int n = qrow0 + mi * 16 + lg * 4 + reg;
        float val = oacc[mi][ds][reg] / lrun[mi][reg];
        ao[((size_t)bb * 2048 + n) * 512 + hh * 64 + ds * 16 + l15] = (bf16)val;
      }
}

// ---------------------------------------------------------------------------
// Output projection GEMM + bias + residual. ao[8192][512] x woT[512][512]^T.
// ---------------------------------------------------------------------------
__global__ __launch_bounds__(256, 2) void gemm_out_kernel(
    const bf16* __restrict__ ao, const bf16* __restrict__ woT,
    const float* __restrict__ bo, const float* __restrict__ x,
    float* __restrict__ out) {
  f32x4 acc[4][4];
  gemm_tile(ao, woT, acc);
  const int tid = threadIdx.x, wave = tid >> 6, lane = tid & 63;
  const int wrow = wave >> 1, wcol = wave & 1;
  const int l15 = lane & 15, lg = lane >> 4;
  const int row0 = blockIdx.x * 128 + wrow * 64;
  const int col0 = blockIdx.y * 128 + wcol * 64;
#pragma unroll
  for (int mi = 0; mi < 4; ++mi) {
#pragma unroll
    for (int ni = 0; ni < 4; ++ni) {
      int c = col0 + ni * 16 + l15;
      float bias = bo[c];
#pragma unroll
      for (int reg = 0; reg < 4; ++reg) {
        int r = row0 + mi * 16 + lg * 4 + reg;
        size_t ofs = (size_t)r * 512 + c;
        out[ofs] = acc[mi][ni][reg] + bias + x[ofs];
      }
    }
  }
}

// ---------------------------------------------------------------------------
extern "C" void kernel_launch(void* const* d_in, const int* in_sizes, int n_in,
                              void* d_out, int out_size, void* d_ws, size_t ws_size,
                              hipStream_t stream) {
  const float* x   = (const float*)d_in[0];
  const float* lnw = (const float*)d_in[1];
  const float* lnb = (const float*)d_in[2];
  const float* wq  = (const float*)d_in[3];
  const float* wk  = (const float*)d_in[4];
  const float* wv  = (const float*)d_in[5];
  const float* bv  = (const float*)d_in[6];
  const float* wo  = (const float*)d_in[7];
  const float* bo  = (const float*)d_in[8];
  const float* pe  = (const float*)d_in[9];
  float* out = (float*)d_out;

  char* ws = (char*)d_ws;
  // workspace layout (bytes): 34 MiB total
  bf16* hbuf  = (bf16*)(ws);               // [8192][512] h, reused as attn-out
  bf16* wqkvT = (bf16*)(ws + 8388608);     // [1536][512]
  bf16* woT   = (bf16*)(ws + 9961472);     // [512][512]
  bf16* qb    = (bf16*)(ws + 10485760);    // [32][2048][64]
  bf16* kb    = (bf16*)(ws + 18874368);    // [32][2048][64]
  bf16* vb    = (bf16*)(ws + 27262976);    // [32][64][2048] (transposed)
  bf16* aob   = hbuf;

  hipLaunchKernelGGL(wtrans_kernel, dim3(16, 16, 4), dim3(32, 8), 0, stream,
                     wq, wk, wv, wo, wqkvT, woT);
  hipLaunchKernelGGL(ln_pe_kernel, dim3(8192), dim3(256), 0, stream,
                     x, lnw, lnb, pe, hbuf);
  hipLaunchKernelGGL(gemm_qkv_kernel, dim3(64, 12), dim3(256), 0, stream,
                     hbuf, wqkvT, bv, qb, kb, vb);
  hipLaunchKernelGGL(attn_kernel, dim3(16, 32), dim3(256), 0, stream,
                     qb, kb, vb, aob);
  hipLaunchKernelGGL(gemm_out_kernel, dim3(64, 4), dim3(256), 0, stream,
                     aob, woT, bo, x, out);
}

// Round 3
// 194.282 us; speedup vs baseline: 1.4340x; 1.4340x over previous
//
#include <hip/hip_runtime.h>

// ---------------------------------------------------------------------------
// SABlock fused pipeline for MI355X (gfx950)
//   x:[4,2048,512] f32 -> LN -> +pe -> QKV proj -> 8-head attn -> out proj -> +x
// bf16 MFMA 16x16x32 everywhere, fp32 accum.
// ---------------------------------------------------------------------------

typedef __bf16 bf16;
typedef __bf16 bf16x2 __attribute__((ext_vector_type(2)));
typedef __bf16 bf16x4 __attribute__((ext_vector_type(4)));
typedef __bf16 bf16x8 __attribute__((ext_vector_type(8)));
typedef float  f32x4  __attribute__((ext_vector_type(4)));

#define MFMA16(a, b, c) __builtin_amdgcn_mfma_f32_16x16x32_bf16((a), (b), (c), 0, 0, 0)

#if __has_builtin(__builtin_amdgcn_exp2f)
#define EXP2(x) __builtin_amdgcn_exp2f(x)
#else
#define EXP2(x) exp2f(x)
#endif

__device__ __forceinline__ void gload16(const void* g, void* l) {
  __builtin_amdgcn_global_load_lds(
      (const __attribute__((address_space(1))) unsigned int*)g,
      (__attribute__((address_space(3))) unsigned int*)l, 16, 0, 0);
}

// ---------------------------------------------------------------------------
// Weight transpose to bf16: dst[o][i] = (bf16)src[i][o], 512x512 each.
// ---------------------------------------------------------------------------
__global__ void wtrans_kernel(const float* __restrict__ wq, const float* __restrict__ wk,
                              const float* __restrict__ wv, const float* __restrict__ wo,
                              bf16* __restrict__ wqkvT, bf16* __restrict__ woT) {
  __shared__ float tile[32][33];
  int z = blockIdx.z;
  const float* src = (z == 0) ? wq : (z == 1) ? wk : (z == 2) ? wv : wo;
  bf16* dst = (z < 3) ? (wqkvT + (size_t)z * 512 * 512) : woT;
  int bx = blockIdx.x, by = blockIdx.y;
  int tx = threadIdx.x, ty = threadIdx.y;
#pragma unroll
  for (int yy = 0; yy < 4; ++yy)
    tile[ty + 8 * yy][tx] = src[(size_t)(by * 32 + ty + 8 * yy) * 512 + bx * 32 + tx];
  __syncthreads();
#pragma unroll
  for (int yy = 0; yy < 4; ++yy)
    dst[(size_t)(bx * 32 + ty + 8 * yy) * 512 + by * 32 + tx] = (bf16)tile[tx][ty + 8 * yy];
}

// ---------------------------------------------------------------------------
// LayerNorm + positional embedding -> bf16 h [8192][512]
// ---------------------------------------------------------------------------
__global__ __launch_bounds__(256) void ln_pe_kernel(const float* __restrict__ x,
                                                    const float* __restrict__ w,
                                                    const float* __restrict__ b,
                                                    const float* __restrict__ pe,
                                                    bf16* __restrict__ h) {
  int row = blockIdx.x;
  int tid = threadIdx.x;
  const float2 xv = *(const float2*)(x + (size_t)row * 512 + tid * 2);
  float s = xv.x + xv.y;
  float ss = xv.x * xv.x + xv.y * xv.y;
#pragma unroll
  for (int off = 32; off; off >>= 1) {
    s += __shfl_xor(s, off);
    ss += __shfl_xor(ss, off);
  }
  __shared__ float ps[4], pss[4];
  int wave = tid >> 6;
  if ((tid & 63) == 0) { ps[wave] = s; pss[wave] = ss; }
  __syncthreads();
  s = ps[0] + ps[1] + ps[2] + ps[3];
  ss = pss[0] + pss[1] + pss[2] + pss[3];
  float mu = s * (1.0f / 512.0f);
  float var = ss * (1.0f / 512.0f) - mu * mu;
  float rs = rsqrtf(var + 1e-5f);
  int n = row & 2047;
  float2 wv2 = *(const float2*)(w + tid * 2);
  float2 bv2 = *(const float2*)(b + tid * 2);
  float2 pv2 = *(const float2*)(pe + (size_t)n * 512 + tid * 2);
  bf16x2 o;
  o[0] = (bf16)((xv.x - mu) * rs * wv2.x + bv2.x + pv2.x);
  o[1] = (bf16)((xv.y - mu) * rs * wv2.y + bv2.y + pv2.y);
  *(bf16x2*)(h + (size_t)row * 512 + tid * 2) = o;
}

// ---------------------------------------------------------------------------
// GEMM mainloop, 2-phase double-buffered: C[128x128] = A[128x512] * Bt[128x512]^T.
// Stage K-step kt+1 into buf^1 while MFMAing kt; ONE barrier per K-step.
// 4 waves 2x2, each 64x64 via 4x4 16x16x32 fragments.
// ---------------------------------------------------------------------------
__device__ __forceinline__ void gemm_tile(const bf16* __restrict__ A,
                                          const bf16* __restrict__ Bt,
                                          f32x4 acc[4][4]) {
  __shared__ char lds[32768];  // [2][ A 8KB | B 8KB ]
  const int tid = threadIdx.x, wave = tid >> 6, lane = tid & 63;
  const int wrow = wave >> 1, wcol = wave & 1;
  const int l15 = lane & 15, lg = lane >> 4;
  const char* Ab = (const char*)A + (size_t)blockIdx.x * 128 * 1024;
  const char* Bb = (const char*)Bt + (size_t)blockIdx.y * 128 * 1024;
  // staging geometry: tile rows are 64B; 1 issue = 16 rows; wave w covers 32 rows
  const int r0 = wave * 32 + (lane >> 2);
  const int cb = (lane & 3) * 16;
  const size_t so = (size_t)r0 * 1024 + cb;

  const f32x4 z = {0.f, 0.f, 0.f, 0.f};
#pragma unroll
  for (int mi = 0; mi < 4; ++mi)
#pragma unroll
    for (int ni = 0; ni < 4; ++ni) acc[mi][ni] = z;

  // prologue: stage kt=0 into buf0
  {
    char* nb = lds;
    gload16(Ab + so, nb + wave * 2048);
    gload16(Ab + so + 16 * 1024, nb + wave * 2048 + 1024);
    gload16(Bb + so, nb + 8192 + wave * 2048);
    gload16(Bb + so + 16 * 1024, nb + 8192 + wave * 2048 + 1024);
  }
  __syncthreads();

  for (int kt = 0; kt < 16; ++kt) {
    if (kt < 15) {  // stage kt+1 into the other buffer; lands by next barrier
      char* nb = lds + ((kt + 1) & 1) * 16384;
      const char* As = Ab + so + (kt + 1) * 64;
      const char* Bs = Bb + so + (kt + 1) * 64;
      gload16(As, nb + wave * 2048);
      gload16(As + 16 * 1024, nb + wave * 2048 + 1024);
      gload16(Bs, nb + 8192 + wave * 2048);
      gload16(Bs + 16 * 1024, nb + 8192 + wave * 2048 + 1024);
    }
    char* lA = lds + (kt & 1) * 16384;
    char* lB = lA + 8192;
    bf16x8 av[4], bv[4];
#pragma unroll
    for (int mi = 0; mi < 4; ++mi)
      av[mi] = *(const bf16x8*)(lA + (wrow * 64 + mi * 16 + l15) * 64 + lg * 16);
#pragma unroll
    for (int ni = 0; ni < 4; ++ni)
      bv[ni] = *(const bf16x8*)(lB + (wcol * 64 + ni * 16 + l15) * 64 + lg * 16);
#pragma unroll
    for (int mi = 0; mi < 4; ++mi)
#pragma unroll
      for (int ni = 0; ni < 4; ++ni)
        acc[mi][ni] = MFMA16(av[mi], bv[ni], acc[mi][ni]);
    __syncthreads();  // drains next-stage loads + protects buf reuse
  }
}

// ---------------------------------------------------------------------------
// QKV projection. q pre-scaled by 1/8 * log2(e) (softmax done in log2 space).
// ---------------------------------------------------------------------------
__global__ __launch_bounds__(256, 3) void gemm_qkv_kernel(
    const bf16* __restrict__ h, const bf16* __restrict__ wqkvT,
    const float* __restrict__ bvec, bf16* __restrict__ qo, bf16* __restrict__ ko,
    bf16* __restrict__ vo) {
  f32x4 acc[4][4];
  gemm_tile(h, wqkvT, acc);
  const int tid = threadIdx.x, wave = tid >> 6, lane = tid & 63;
  const int wrow = wave >> 1, wcol = wave & 1;
  const int l15 = lane & 15, lg = lane >> 4;
  const int row0 = blockIdx.x * 128 + wrow * 64;
  const int col0 = blockIdx.y * 128 + wcol * 64;
#pragma unroll
  for (int mi = 0; mi < 4; ++mi) {
#pragma unroll
    for (int ni = 0; ni < 4; ++ni) {
      int c = col0 + ni * 16 + l15;
      int proj = c >> 9;
      int wc = c & 511;
      int head = wc >> 6, d = wc & 63;
      int rb = row0 + mi * 16 + lg * 4;
      int bb = rb >> 11, n = rb & 2047;
      if (proj == 2) {
        float bias = bvec[wc];
        bf16x4 pv;
#pragma unroll
        for (int reg = 0; reg < 4; ++reg) pv[reg] = (bf16)(acc[mi][ni][reg] + bias);
        *(bf16x4*)(vo + ((size_t)(bb * 8 + head) * 64 + d) * 2048 + n) = pv;
      } else if (proj == 0) {
#pragma unroll
        for (int reg = 0; reg < 4; ++reg)
          qo[((size_t)(bb * 8 + head) * 2048 + (n + reg)) * 64 + d] =
              (bf16)(acc[mi][ni][reg] * (0.125f * 1.44269504f));
      } else {
#pragma unroll
        for (int reg = 0; reg < 4; ++reg)
          ko[((size_t)(bb * 8 + head) * 2048 + (n + reg)) * 64 + d] =
              (bf16)acc[mi][ni][reg];
      }
    }
  }
}

// ---------------------------------------------------------------------------
// Flash attention, swapped-QK^T form. 1-D grid 512 blocks, XCD-pinned so all
// 16 q-tiles of one bh share one XCD's L2 (4 heads x 512KB KV = 2MB < 4MB).
// 4 waves x 32 q-rows; KV tiles of 64; double-buffered K/V via global_load_lds
// with pre-swizzled source (swizzle ^= (row&7)<<4); ONE barrier per tile.
// S^T = mfma(K,Q): lane's q = lane&15 -> in-lane row reduce + 2 shuffles;
// P stored [q][key] -> vectorized b64 writes, b128 A-frag reads.
// ---------------------------------------------------------------------------
__global__ __launch_bounds__(256, 2) void attn_kernel(const bf16* __restrict__ q,
                                                      const bf16* __restrict__ k,
                                                      const bf16* __restrict__ v,
                                                      bf16* __restrict__ ao) {
  __shared__ char lds[49152];  // [2][K 8KB | V 8KB] + P 4 x 4KB
  const int tid = threadIdx.x, wave = tid >> 6, lane = tid & 63;
  const int l15 = lane & 15, lg = lane >> 4;
  const int swzr = (l15 & 7) << 4;  // read-side swizzle (row bits)

  // XCD-pinning decode: xcd = bid&7 == bh&7 (round-robin dispatch)
  const int bid = blockIdx.x;
  const int xcd = bid & 7, slot = bid >> 3;
  const int bh = xcd + 8 * (slot >> 4);
  const int qt = slot & 15;
  const int bb = bh >> 3, hh = bh & 7;

  const char* ksrc = (const char*)(k + (size_t)bh * 2048 * 64);   // rowstride 128B
  const char* vsrc = (const char*)(v + (size_t)bh * 64 * 2048);   // rowstride 4096B
  // staging geometry: 1 issue = 8 rows of 128B; wave w covers rows 16w..16w+15
  const int r0 = wave * 16 + (lane >> 3);
  const int colb = (lane & 7) * 16;
  const size_t ko0 = (size_t)r0 * 128 + (colb ^ ((r0 & 7) << 4));   // inverse-swizzled src
  const size_t vo0 = (size_t)r0 * 4096 + (colb ^ ((r0 & 7) << 4));
  char* Pw = lds + 32768 + wave * 4096;

  // Q fragments (B-operand layout == contiguous row reads), pre-scaled
  const bf16* qbase = q + ((size_t)bh * 2048 + qt * 128 + wave * 32) * 64;
  bf16x8 qf[2][2];
#pragma unroll
  for (int mi = 0; mi < 2; ++mi)
#pragma unroll
    for (int dk = 0; dk < 2; ++dk)
      qf[mi][dk] = *(const bf16x8*)(qbase + (mi * 16 + l15) * 64 + dk * 32 + lg * 8);

  const f32x4 z = {0.f, 0.f, 0.f, 0.f};
  f32x4 oacc[2][4];
  float mrun[2] = {-1e30f, -1e30f}, lrun[2] = {0.f, 0.f};
#pragma unroll
  for (int mi = 0; mi < 2; ++mi)
#pragma unroll
    for (int ds = 0; ds < 4; ++ds) oacc[mi][ds] = z;

  // prologue: stage tile 0 -> buf0
  gload16(ksrc + ko0, lds + wave * 2048);
  gload16(ksrc + ko0 + 1024, lds + wave * 2048 + 1024);
  gload16(vsrc + vo0, lds + 8192 + wave * 2048);
  gload16(vsrc + vo0 + 8 * 4096, lds + 8192 + wave * 2048 + 1024);
  __syncthreads();

  for (int t = 0; t < 32; ++t) {
    if (t + 1 < 32) {  // stage t+1 into other buffer; in flight across compute
      char* nb = lds + ((t + 1) & 1) * 16384;
      const char* ks = ksrc + (size_t)(t + 1) * 8192 + ko0;
      const char* vs = vsrc + (size_t)(t + 1) * 128 + vo0;
      gload16(ks, nb + wave * 2048);
      gload16(ks + 1024, nb + wave * 2048 + 1024);
      gload16(vs, nb + 8192 + wave * 2048);
      gload16(vs + 8 * 4096, nb + 8192 + wave * 2048 + 1024);
    }
    char* Ksh = lds + (t & 1) * 16384;
    char* Vsh = Ksh + 8192;

    // K fragments (A-operand), hoisted for both mi
    bf16x8 kf[4][2];
#pragma unroll
    for (int kt = 0; kt < 4; ++kt)
#pragma unroll
      for (int dk = 0; dk < 2; ++dk)
        kf[kt][dk] = *(const bf16x8*)(Ksh + (kt * 16 + l15) * 128 +
                                      ((dk * 64 + lg * 16) ^ swzr));
    // S^T = K x Q : col = q (lane&15), row = key
    f32x4 sacc[2][4];
#pragma unroll
    for (int mi = 0; mi < 2; ++mi)
#pragma unroll
      for (int kt = 0; kt < 4; ++kt) sacc[mi][kt] = z;
#pragma unroll
    for (int mi = 0; mi < 2; ++mi)
#pragma unroll
      for (int dk = 0; dk < 2; ++dk)
#pragma unroll
        for (int kt = 0; kt < 4; ++kt)
          sacc[mi][kt] = MFMA16(kf[kt][dk], qf[mi][dk], sacc[mi][kt]);

    // online softmax in log2 space; lane owns q-col = l15, 16 of 64 keys
#pragma unroll
    for (int mi = 0; mi < 2; ++mi) {
      float mt = sacc[mi][0][0];
#pragma unroll
      for (int kt = 0; kt < 4; ++kt)
#pragma unroll
        for (int reg = 0; reg < 4; ++reg)
          if (kt || reg) mt = fmaxf(mt, sacc[mi][kt][reg]);
      mt = fmaxf(mt, __shfl_xor(mt, 16));
      mt = fmaxf(mt, __shfl_xor(mt, 32));
      float mn = fmaxf(mrun[mi], mt);
      float rs = 0.f;
      float p[4][4];
#pragma unroll
      for (int kt = 0; kt < 4; ++kt)
#pragma unroll
        for (int reg = 0; reg < 4; ++reg) {
          p[kt][reg] = EXP2(sacc[mi][kt][reg] - mn);
          rs += p[kt][reg];
        }
      rs += __shfl_xor(rs, 16);
      rs += __shfl_xor(rs, 32);
      // P -> LDS [q][key], b64 vectorized, swizzled
#pragma unroll
      for (int kt = 0; kt < 4; ++kt) {
        bf16x4 pv;
#pragma unroll
        for (int reg = 0; reg < 4; ++reg) pv[reg] = (bf16)p[kt][reg];
        *(bf16x4*)(Pw + (mi * 16 + l15) * 128 + ((kt * 32 + lg * 8) ^ swzr)) = pv;
      }
      // rescale only if any q-row's max grew (skip saves exp+shfl+mults)
      if (__any(mt > mrun[mi])) {
        float sc = EXP2(mrun[mi] - mn);
        mrun[mi] = mn;
        lrun[mi] *= sc;
        float scr[4];
#pragma unroll
        for (int reg = 0; reg < 4; ++reg) scr[reg] = __shfl(sc, lg * 4 + reg);
#pragma unroll
        for (int ds = 0; ds < 4; ++ds)
#pragma unroll
          for (int reg = 0; reg < 4; ++reg) oacc[mi][ds][reg] *= scr[reg];
      }
      lrun[mi] += rs;
    }

    // PV: O[q][d] += P[q][key] x V[key][d]; vf from V^T LDS [d][key]
#pragma unroll
    for (int ks = 0; ks < 2; ++ks) {
      bf16x8 vf[4];
#pragma unroll
      for (int ds = 0; ds < 4; ++ds)
        vf[ds] = *(const bf16x8*)(Vsh + (ds * 16 + l15) * 128 +
                                  ((ks * 64 + lg * 16) ^ swzr));
#pragma unroll
      for (int mi = 0; mi < 2; ++mi) {
        bf16x8 pf = *(const bf16x8*)(Pw + (mi * 16 + l15) * 128 +
                                     ((ks * 64 + lg * 16) ^ swzr));
#pragma unroll
        for (int ds = 0; ds < 4; ++ds)
          oacc[mi][ds] = MFMA16(pf, vf[ds], oacc[mi][ds]);
      }
    }
    __syncthreads();  // drains t+1 staging; all waves done with buf t
  }

  // epilogue: redistribute 1/l from softmax-land (q=lane&15) to PV-land rows
  const int qrow0 = qt * 128 + wave * 32;
#pragma unroll
  for (int mi = 0; mi < 2; ++mi) {
#if __has_builtin(__builtin_amdgcn_rcpf)
    float rin = __builtin_amdgcn_rcpf(lrun[mi]);
#else
    float rin = 1.0f / lrun[mi];
#endif
    float rr[4];
#pragma unroll
    for (int reg = 0; reg < 4; ++reg) rr[reg] = __shfl(rin, lg * 4 + reg);
#pragma unroll
    for (int ds = 0; ds < 4; ++ds)
#pragma unroll
      for (int reg = 0; reg < 4; ++reg) {
        int n = qrow0 + mi * 16 + lg * 4 + reg;
        ao[((size_t)bb * 2048 + n) * 512 + hh * 64 + ds * 16 + l15] =
            (bf16)(oacc[mi][ds][reg] * rr[reg]);
      }
  }
}

// ---------------------------------------------------------------------------
// Output projection + bias + residual.
// ---------------------------------------------------------------------------
__global__ __launch_bounds__(256, 3) void gemm_out_kernel(
    const bf16* __restrict__ ao, const bf16* __restrict__ woT,
    const float* __restrict__ bo, const float* __restrict__ x,
    float* __restrict__ out) {
  f32x4 acc[4][4];
  gemm_tile(ao, woT, acc);
  const int tid = threadIdx.x, wave = tid >> 6, lane = tid & 63;
  const int wrow = wave >> 1, wcol = wave & 1;
  const int l15 = lane & 15, lg = lane >> 4;
  const int row0 = blockIdx.x * 128 + wrow * 64;
  const int col0 = blockIdx.y * 128 + wcol * 64;
#pragma unroll
  for (int mi = 0; mi < 4; ++mi) {
#pragma unroll
    for (int ni = 0; ni < 4; ++ni) {
      int c = col0 + ni * 16 + l15;
      float bias = bo[c];
#pragma unroll
      for (int reg = 0; reg < 4; ++reg) {
        int r = row0 + mi * 16 + lg * 4 + reg;
        size_t ofs = (size_t)r * 512 + c;
        out[ofs] = acc[mi][ni][reg] + bias + x[ofs];
      }
    }
  }
}

// ---------------------------------------------------------------------------
extern "C" void kernel_launch(void* const* d_in, const int* in_sizes, int n_in,
                              void* d_out, int out_size, void* d_ws, size_t ws_size,
                              hipStream_t stream) {
  const float* x   = (const float*)d_in[0];
  const float* lnw = (const float*)d_in[1];
  const float* lnb = (const float*)d_in[2];
  const float* wq  = (const float*)d_in[3];
  const float* wk  = (const float*)d_in[4];
  const float* wv  = (const float*)d_in[5];
  const float* bv  = (const float*)d_in[6];
  const float* wo  = (const float*)d_in[7];
  const float* bo  = (const float*)d_in[8];
  const float* pe  = (const float*)d_in[9];
  float* out = (float*)d_out;

  char* ws = (char*)d_ws;
  bf16* hbuf  = (bf16*)(ws);               // [8192][512] h, reused as attn-out
  bf16* wqkvT = (bf16*)(ws + 8388608);     // [1536][512]
  bf16* woT   = (bf16*)(ws + 9961472);     // [512][512]
  bf16* qb    = (bf16*)(ws + 10485760);    // [32][2048][64] (pre-scaled)
  bf16* kb    = (bf16*)(ws + 18874368);    // [32][2048][64]
  bf16* vb    = (bf16*)(ws + 27262976);    // [32][64][2048] (transposed)
  bf16* aob   = hbuf;

  hipLaunchKernelGGL(wtrans_kernel, dim3(16, 16, 4), dim3(32, 8), 0, stream,
                     wq, wk, wv, wo, wqkvT, woT);
  hipLaunchKernelGGL(ln_pe_kernel, dim3(8192), dim3(256), 0, stream,
                     x, lnw, lnb, pe, hbuf);
  hipLaunchKernelGGL(gemm_qkv_kernel, dim3(64, 12), dim3(256), 0, stream,
                     hbuf, wqkvT, bv, qb, kb, vb);
  hipLaunchKernelGGL(attn_kernel, dim3(512), dim3(256), 0, stream,
                     qb, kb, vb, aob);
  hipLaunchKernelGGL(gemm_out_kernel, dim3(64, 4), dim3(256), 0, stream,
                     aob, woT, bo, x, out);
}

// Round 4
// 179.469 us; speedup vs baseline: 1.5524x; 1.0825x over previous
//
#include <hip/hip_runtime.h>

// ---------------------------------------------------------------------------
// SABlock fused pipeline for MI355X (gfx950)
//   x:[4,2048,512] f32 -> LN -> +pe -> QKV proj -> 8-head attn -> out proj -> +x
// bf16 MFMA 16x16x32 everywhere, fp32 accum.
// ---------------------------------------------------------------------------

typedef __bf16 bf16;
typedef __bf16 bf16x2 __attribute__((ext_vector_type(2)));
typedef __bf16 bf16x4 __attribute__((ext_vector_type(4)));
typedef __bf16 bf16x8 __attribute__((ext_vector_type(8)));
typedef float  f32x4  __attribute__((ext_vector_type(4)));

#define MFMA16(a, b, c) __builtin_amdgcn_mfma_f32_16x16x32_bf16((a), (b), (c), 0, 0, 0)

#if __has_builtin(__builtin_amdgcn_exp2f)
#define EXP2(x) __builtin_amdgcn_exp2f(x)
#else
#define EXP2(x) exp2f(x)
#endif

__device__ __forceinline__ void gload16(const void* g, void* l) {
  __builtin_amdgcn_global_load_lds(
      (const __attribute__((address_space(1))) unsigned int*)g,
      (__attribute__((address_space(3))) unsigned int*)l, 16, 0, 0);
}

// ---------------------------------------------------------------------------
// Weight transpose to bf16: dst[o][i] = (bf16)src[i][o], 512x512 each.
// ---------------------------------------------------------------------------
__global__ void wtrans_kernel(const float* __restrict__ wq, const float* __restrict__ wk,
                              const float* __restrict__ wv, const float* __restrict__ wo,
                              bf16* __restrict__ wqkvT, bf16* __restrict__ woT) {
  __shared__ float tile[32][33];
  int z = blockIdx.z;
  const float* src = (z == 0) ? wq : (z == 1) ? wk : (z == 2) ? wv : wo;
  bf16* dst = (z < 3) ? (wqkvT + (size_t)z * 512 * 512) : woT;
  int bx = blockIdx.x, by = blockIdx.y;
  int tx = threadIdx.x, ty = threadIdx.y;
#pragma unroll
  for (int yy = 0; yy < 4; ++yy)
    tile[ty + 8 * yy][tx] = src[(size_t)(by * 32 + ty + 8 * yy) * 512 + bx * 32 + tx];
  __syncthreads();
#pragma unroll
  for (int yy = 0; yy < 4; ++yy)
    dst[(size_t)(bx * 32 + ty + 8 * yy) * 512 + by * 32 + tx] = (bf16)tile[tx][ty + 8 * yy];
}

// ---------------------------------------------------------------------------
// LayerNorm + positional embedding -> bf16 h [8192][512].
// One row per wave, no block barrier: float4 x2 loads, bf16x8 store.
// ---------------------------------------------------------------------------
__global__ __launch_bounds__(256) void ln_pe_kernel(const float* __restrict__ x,
                                                    const float* __restrict__ w,
                                                    const float* __restrict__ b,
                                                    const float* __restrict__ pe,
                                                    bf16* __restrict__ h) {
  const int row = blockIdx.x * 4 + (threadIdx.x >> 6);
  const int lane = threadIdx.x & 63;
  const float4* xr = (const float4*)(x + (size_t)row * 512) + lane * 2;
  const float4 a = xr[0], c = xr[1];
  float s = a.x + a.y + a.z + a.w + c.x + c.y + c.z + c.w;
  float ss = a.x * a.x + a.y * a.y + a.z * a.z + a.w * a.w +
             c.x * c.x + c.y * c.y + c.z * c.z + c.w * c.w;
#pragma unroll
  for (int off = 1; off <= 32; off <<= 1) {
    s += __shfl_xor(s, off);
    ss += __shfl_xor(ss, off);
  }
  const float mu = s * (1.0f / 512.0f);
  const float var = ss * (1.0f / 512.0f) - mu * mu;
  const float rs = rsqrtf(var + 1e-5f);
  const float4* wr = (const float4*)w + lane * 2;
  const float4* br = (const float4*)b + lane * 2;
  const float4* pr = (const float4*)(pe + (size_t)(row & 2047) * 512) + lane * 2;
  const float4 w0 = wr[0], w1 = wr[1], b0 = br[0], b1 = br[1], p0 = pr[0], p1 = pr[1];
  bf16x8 o;
  o[0] = (bf16)((a.x - mu) * rs * w0.x + b0.x + p0.x);
  o[1] = (bf16)((a.y - mu) * rs * w0.y + b0.y + p0.y);
  o[2] = (bf16)((a.z - mu) * rs * w0.z + b0.z + p0.z);
  o[3] = (bf16)((a.w - mu) * rs * w0.w + b0.w + p0.w);
  o[4] = (bf16)((c.x - mu) * rs * w1.x + b1.x + p1.x);
  o[5] = (bf16)((c.y - mu) * rs * w1.y + b1.y + p1.y);
  o[6] = (bf16)((c.z - mu) * rs * w1.z + b1.z + p1.z);
  o[7] = (bf16)((c.w - mu) * rs * w1.w + b1.w + p1.w);
  *(bf16x8*)(h + (size_t)row * 512 + lane * 8) = o;
}

// ---------------------------------------------------------------------------
// GEMM mainloop, 2-phase double-buffered: C[128x128] = A[128x512] * Bt[128x512]^T.
// ---------------------------------------------------------------------------
__device__ __forceinline__ void gemm_tile(const bf16* __restrict__ A,
                                          const bf16* __restrict__ Bt,
                                          f32x4 acc[4][4]) {
  __shared__ char lds[32768];  // [2][ A 8KB | B 8KB ]
  const int tid = threadIdx.x, wave = tid >> 6, lane = tid & 63;
  const int wrow = wave >> 1, wcol = wave & 1;
  const int l15 = lane & 15, lg = lane >> 4;
  const char* Ab = (const char*)A + (size_t)blockIdx.x * 128 * 1024;
  const char* Bb = (const char*)Bt + (size_t)blockIdx.y * 128 * 1024;
  const int r0 = wave * 32 + (lane >> 2);
  const int cb = (lane & 3) * 16;
  const size_t so = (size_t)r0 * 1024 + cb;

  const f32x4 z = {0.f, 0.f, 0.f, 0.f};
#pragma unroll
  for (int mi = 0; mi < 4; ++mi)
#pragma unroll
    for (int ni = 0; ni < 4; ++ni) acc[mi][ni] = z;

  {
    char* nb = lds;
    gload16(Ab + so, nb + wave * 2048);
    gload16(Ab + so + 16 * 1024, nb + wave * 2048 + 1024);
    gload16(Bb + so, nb + 8192 + wave * 2048);
    gload16(Bb + so + 16 * 1024, nb + 8192 + wave * 2048 + 1024);
  }
  __syncthreads();

  for (int kt = 0; kt < 16; ++kt) {
    if (kt < 15) {
      char* nb = lds + ((kt + 1) & 1) * 16384;
      const char* As = Ab + so + (kt + 1) * 64;
      const char* Bs = Bb + so + (kt + 1) * 64;
      gload16(As, nb + wave * 2048);
      gload16(As + 16 * 1024, nb + wave * 2048 + 1024);
      gload16(Bs, nb + 8192 + wave * 2048);
      gload16(Bs + 16 * 1024, nb + 8192 + wave * 2048 + 1024);
    }
    char* lA = lds + (kt & 1) * 16384;
    char* lB = lA + 8192;
    bf16x8 av[4], bv[4];
#pragma unroll
    for (int mi = 0; mi < 4; ++mi)
      av[mi] = *(const bf16x8*)(lA + (wrow * 64 + mi * 16 + l15) * 64 + lg * 16);
#pragma unroll
    for (int ni = 0; ni < 4; ++ni)
      bv[ni] = *(const bf16x8*)(lB + (wcol * 64 + ni * 16 + l15) * 64 + lg * 16);
    __builtin_amdgcn_s_setprio(1);
#pragma unroll
    for (int mi = 0; mi < 4; ++mi)
#pragma unroll
      for (int ni = 0; ni < 4; ++ni)
        acc[mi][ni] = MFMA16(av[mi], bv[ni], acc[mi][ni]);
    __builtin_amdgcn_s_setprio(0);
    __syncthreads();
  }
}

// ---------------------------------------------------------------------------
// QKV projection. q pre-scaled by 1/8 * log2(e) (softmax done in log2 space).
// ---------------------------------------------------------------------------
__global__ __launch_bounds__(256, 3) void gemm_qkv_kernel(
    const bf16* __restrict__ h, const bf16* __restrict__ wqkvT,
    const float* __restrict__ bvec, bf16* __restrict__ qo, bf16* __restrict__ ko,
    bf16* __restrict__ vo) {
  f32x4 acc[4][4];
  gemm_tile(h, wqkvT, acc);
  const int tid = threadIdx.x, wave = tid >> 6, lane = tid & 63;
  const int wrow = wave >> 1, wcol = wave & 1;
  const int l15 = lane & 15, lg = lane >> 4;
  const int row0 = blockIdx.x * 128 + wrow * 64;
  const int col0 = blockIdx.y * 128 + wcol * 64;
#pragma unroll
  for (int mi = 0; mi < 4; ++mi) {
#pragma unroll
    for (int ni = 0; ni < 4; ++ni) {
      int c = col0 + ni * 16 + l15;
      int proj = c >> 9;
      int wc = c & 511;
      int head = wc >> 6, d = wc & 63;
      int rb = row0 + mi * 16 + lg * 4;
      int bb = rb >> 11, n = rb & 2047;
      if (proj == 2) {
        float bias = bvec[wc];
        bf16x4 pv;
#pragma unroll
        for (int reg = 0; reg < 4; ++reg) pv[reg] = (bf16)(acc[mi][ni][reg] + bias);
        *(bf16x4*)(vo + ((size_t)(bb * 8 + head) * 64 + d) * 2048 + n) = pv;
      } else if (proj == 0) {
#pragma unroll
        for (int reg = 0; reg < 4; ++reg)
          qo[((size_t)(bb * 8 + head) * 2048 + (n + reg)) * 64 + d] =
              (bf16)(acc[mi][ni][reg] * (0.125f * 1.44269504f));
      } else {
#pragma unroll
        for (int reg = 0; reg < 4; ++reg)
          ko[((size_t)(bb * 8 + head) * 2048 + (n + reg)) * 64 + d] =
              (bf16)acc[mi][ni][reg];
      }
    }
  }
}

// ---------------------------------------------------------------------------
// Flash attention, swapped-QK^T. 1024 blocks XCD-pinned (4 bh x 512KB = 2MB/XCD L2).
// 4 waves x 16 q-rows (64-row blocks) -> 4096 waves = 16/CU = 4/SIMD.
// LDS 40KB -> 4 blocks/CU. KV tiles of 64, double-buffered global_load_lds with
// pre-swizzled source; ONE barrier per tile. Defer-max THR=8 (11.5 log2 units).
// ---------------------------------------------------------------------------
__global__ __launch_bounds__(256, 4) void attn_kernel(const bf16* __restrict__ q,
                                                      const bf16* __restrict__ k,
                                                      const bf16* __restrict__ v,
                                                      bf16* __restrict__ ao) {
  __shared__ char lds[40960];  // [2][K 8KB | V 8KB] + 4 x P 2KB
  const int tid = threadIdx.x, wave = tid >> 6, lane = tid & 63;
  const int l15 = lane & 15, lg = lane >> 4;
  const int swzr = (l15 & 7) << 4;

  const int bid = blockIdx.x;
  const int xcd = bid & 7, slot = bid >> 3;      // 1024 blocks
  const int bh = xcd + 8 * (slot >> 5);          // 4 bh-groups per XCD
  const int qt = slot & 31;                      // 32 q-tiles of 64 rows
  const int bb = bh >> 3, hh = bh & 7;

  const char* ksrc = (const char*)(k + (size_t)bh * 2048 * 64);   // rowstride 128B
  const char* vsrc = (const char*)(v + (size_t)bh * 64 * 2048);   // rowstride 4096B
  const int r0 = wave * 16 + (lane >> 3);
  const int colb = (lane & 7) * 16;
  const size_t ko0 = (size_t)r0 * 128 + (colb ^ ((r0 & 7) << 4));
  const size_t vo0 = (size_t)r0 * 4096 + (colb ^ ((r0 & 7) << 4));
  char* Pw = lds + 32768 + wave * 2048;

  // Q fragments (B-operand), pre-scaled by 0.125*log2e
  const bf16* qbase = q + ((size_t)bh * 2048 + qt * 64 + wave * 16) * 64;
  bf16x8 qf[2];
#pragma unroll
  for (int dk = 0; dk < 2; ++dk)
    qf[dk] = *(const bf16x8*)(qbase + l15 * 64 + dk * 32 + lg * 8);

  const f32x4 z = {0.f, 0.f, 0.f, 0.f};
  f32x4 oacc[4] = {z, z, z, z};
  float mrun = -1e30f, lrun = 0.f;

  // prologue: stage tile 0 -> buf0
  gload16(ksrc + ko0, lds + wave * 2048);
  gload16(ksrc + ko0 + 1024, lds + wave * 2048 + 1024);
  gload16(vsrc + vo0, lds + 8192 + wave * 2048);
  gload16(vsrc + vo0 + 8 * 4096, lds + 8192 + wave * 2048 + 1024);
  __syncthreads();

  for (int t = 0; t < 32; ++t) {
    if (t + 1 < 32) {  // stage t+1 into other buffer; in flight across compute
      char* nb = lds + ((t + 1) & 1) * 16384;
      const char* ks = ksrc + (size_t)(t + 1) * 8192 + ko0;
      const char* vs = vsrc + (size_t)(t + 1) * 128 + vo0;
      gload16(ks, nb + wave * 2048);
      gload16(ks + 1024, nb + wave * 2048 + 1024);
      gload16(vs, nb + 8192 + wave * 2048);
      gload16(vs + 8 * 4096, nb + 8192 + wave * 2048 + 1024);
    }
    char* Ksh = lds + (t & 1) * 16384;
    char* Vsh = Ksh + 8192;

    // S^T = K x Q : col = q (l15), row = key (kt*16 + lg*4 + reg)
    __builtin_amdgcn_s_setprio(1);
    bf16x8 kf[4][2];
#pragma unroll
    for (int kt = 0; kt < 4; ++kt)
#pragma unroll
      for (int dk = 0; dk < 2; ++dk)
        kf[kt][dk] = *(const bf16x8*)(Ksh + (kt * 16 + l15) * 128 +
                                      ((dk * 64 + lg * 16) ^ swzr));
    f32x4 sacc[4] = {z, z, z, z};
#pragma unroll
    for (int dk = 0; dk < 2; ++dk)
#pragma unroll
      for (int kt = 0; kt < 4; ++kt)
        sacc[kt] = MFMA16(kf[kt][dk], qf[dk], sacc[kt]);
    __builtin_amdgcn_s_setprio(0);

    // online softmax (log2 space); lane owns q-col l15, 16 of 64 keys
    float mt = fmaxf(fmaxf(sacc[0][0], sacc[0][1]), fmaxf(sacc[0][2], sacc[0][3]));
#pragma unroll
    for (int kt = 1; kt < 4; ++kt)
      mt = fmaxf(mt, fmaxf(fmaxf(sacc[kt][0], sacc[kt][1]),
                           fmaxf(sacc[kt][2], sacc[kt][3])));
    mt = fmaxf(mt, __shfl_xor(mt, 16));
    mt = fmaxf(mt, __shfl_xor(mt, 32));
    // defer-max: only rescale when max grew by > 8 nats (11.5 log2 units)
    if (__any(mt > mrun + 11.5f)) {
      float mn = fmaxf(mrun, mt);
      float sc = EXP2(mrun - mn);
      mrun = mn;
      lrun *= sc;
      float scr[4];
#pragma unroll
      for (int reg = 0; reg < 4; ++reg) scr[reg] = __shfl(sc, lg * 4 + reg);
#pragma unroll
      for (int ds = 0; ds < 4; ++ds)
#pragma unroll
        for (int reg = 0; reg < 4; ++reg) oacc[ds][reg] *= scr[reg];
    }
    float rs = 0.f;
#pragma unroll
    for (int kt = 0; kt < 4; ++kt) {
      bf16x4 pv;
#pragma unroll
      for (int reg = 0; reg < 4; ++reg) {
        float p = EXP2(sacc[kt][reg] - mrun);
        pv[reg] = (bf16)p;
        rs += p;
      }
      *(bf16x4*)(Pw + l15 * 128 + ((kt * 32 + lg * 8) ^ swzr)) = pv;
    }
    rs += __shfl_xor(rs, 16);
    rs += __shfl_xor(rs, 32);
    lrun += rs;

    // PV: O[q][d] += P[q][key] x V^T[d][key]
    __builtin_amdgcn_s_setprio(1);
#pragma unroll
    for (int ks = 0; ks < 2; ++ks) {
      bf16x8 pf = *(const bf16x8*)(Pw + l15 * 128 + ((ks * 64 + lg * 16) ^ swzr));
#pragma unroll
      for (int ds = 0; ds < 4; ++ds) {
        bf16x8 vf = *(const bf16x8*)(Vsh + (ds * 16 + l15) * 128 +
                                     ((ks * 64 + lg * 16) ^ swzr));
        oacc[ds] = MFMA16(pf, vf, oacc[ds]);
      }
    }
    __builtin_amdgcn_s_setprio(0);
    __syncthreads();  // drains t+1 staging; all waves done with buf t
  }

  // epilogue: redistribute 1/l from softmax-land (q=l15) to PV-land rows
  const int qrow0 = qt * 64 + wave * 16;
#if __has_builtin(__builtin_amdgcn_rcpf)
  float rin = __builtin_amdgcn_rcpf(lrun);
#else
  float rin = 1.0f / lrun;
#endif
  float rr[4];
#pragma unroll
  for (int reg = 0; reg < 4; ++reg) rr[reg] = __shfl(rin, lg * 4 + reg);
#pragma unroll
  for (int ds = 0; ds < 4; ++ds)
#pragma unroll
    for (int reg = 0; reg < 4; ++reg) {
      int n = qrow0 + lg * 4 + reg;
      ao[((size_t)bb * 2048 + n) * 512 + hh * 64 + ds * 16 + l15] =
          (bf16)(oacc[ds][reg] * rr[reg]);
    }
}

// ---------------------------------------------------------------------------
// Output projection + bias + residual.
// ---------------------------------------------------------------------------
__global__ __launch_bounds__(256, 3) void gemm_out_kernel(
    const bf16* __restrict__ ao, const bf16* __restrict__ woT,
    const float* __restrict__ bo, const float* __restrict__ x,
    float* __restrict__ out) {
  f32x4 acc[4][4];
  gemm_tile(ao, woT, acc);
  const int tid = threadIdx.x, wave = tid >> 6, lane = tid & 63;
  const int wrow = wave >> 1, wcol = wave & 1;
  const int l15 = lane & 15, lg = lane >> 4;
  const int row0 = blockIdx.x * 128 + wrow * 64;
  const int col0 = blockIdx.y * 128 + wcol * 64;
#pragma unroll
  for (int mi = 0; mi < 4; ++mi) {
#pragma unroll
    for (int ni = 0; ni < 4; ++ni) {
      int c = col0 + ni * 16 + l15;
      float bias = bo[c];
#pragma unroll
      for (int reg = 0; reg < 4; ++reg) {
        int r = row0 + mi * 16 + lg * 4 + reg;
        size_t ofs = (size_t)r * 512 + c;
        out[ofs] = acc[mi][ni][reg] + bias + x[ofs];
      }
    }
  }
}

// ---------------------------------------------------------------------------
extern "C" void kernel_launch(void* const* d_in, const int* in_sizes, int n_in,
                              void* d_out, int out_size, void* d_ws, size_t ws_size,
                              hipStream_t stream) {
  const float* x   = (const float*)d_in[0];
  const float* lnw = (const float*)d_in[1];
  const float* lnb = (const float*)d_in[2];
  const float* wq  = (const float*)d_in[3];
  const float* wk  = (const float*)d_in[4];
  const float* wv  = (const float*)d_in[5];
  const float* bv  = (const float*)d_in[6];
  const float* wo  = (const float*)d_in[7];
  const float* bo  = (const float*)d_in[8];
  const float* pe  = (const float*)d_in[9];
  float* out = (float*)d_out;

  char* ws = (char*)d_ws;
  bf16* hbuf  = (bf16*)(ws);               // [8192][512] h, reused as attn-out
  bf16* wqkvT = (bf16*)(ws + 8388608);     // [1536][512]
  bf16* woT   = (bf16*)(ws + 9961472);     // [512][512]
  bf16* qb    = (bf16*)(ws + 10485760);    // [32][2048][64] (pre-scaled)
  bf16* kb    = (bf16*)(ws + 18874368);    // [32][2048][64]
  bf16* vb    = (bf16*)(ws + 27262976);    // [32][64][2048] (transposed)
  bf16* aob   = hbuf;

  hipLaunchKernelGGL(wtrans_kernel, dim3(16, 16, 4), dim3(32, 8), 0, stream,
                     wq, wk, wv, wo, wqkvT, woT);
  hipLaunchKernelGGL(ln_pe_kernel, dim3(2048), dim3(256), 0, stream,
                     x, lnw, lnb, pe, hbuf);
  hipLaunchKernelGGL(gemm_qkv_kernel, dim3(64, 12), dim3(256), 0, stream,
                     hbuf, wqkvT, bv, qb, kb, vb);
  hipLaunchKernelGGL(attn_kernel, dim3(1024), dim3(256), 0, stream,
                     qb, kb, vb, aob);
  hipLaunchKernelGGL(gemm_out_kernel, dim3(64, 4), dim3(256), 0, stream,
                     aob, woT, bo, x, out);
}

// Round 5
// 169.746 us; speedup vs baseline: 1.6413x; 1.0573x over previous
//
#include <hip/hip_runtime.h>

// ---------------------------------------------------------------------------
// SABlock fused pipeline for MI355X (gfx950)
//   x:[4,2048,512] f32 -> LN -> +pe -> QKV proj -> 8-head attn -> out proj -> +x
// bf16 MFMA, fp32 accum. Attention uses 32x32x16 MFMA with in-register P.
// ---------------------------------------------------------------------------

typedef __bf16 bf16;
typedef __bf16 bf16x2 __attribute__((ext_vector_type(2)));
typedef __bf16 bf16x4 __attribute__((ext_vector_type(4)));
typedef __bf16 bf16x8 __attribute__((ext_vector_type(8)));
typedef float  f32x4  __attribute__((ext_vector_type(4)));
typedef float  f32x16 __attribute__((ext_vector_type(16)));
typedef unsigned int u32;
typedef u32 u32x4 __attribute__((ext_vector_type(4)));

#define MFMA16(a, b, c) __builtin_amdgcn_mfma_f32_16x16x32_bf16((a), (b), (c), 0, 0, 0)
#define MFMA32(a, b, c) __builtin_amdgcn_mfma_f32_32x32x16_bf16((a), (b), (c), 0, 0, 0)

#if __has_builtin(__builtin_amdgcn_exp2f)
#define EXP2(x) __builtin_amdgcn_exp2f(x)
#else
#define EXP2(x) exp2f(x)
#endif

__device__ __forceinline__ void gload16(const void* g, void* l) {
  __builtin_amdgcn_global_load_lds(
      (const __attribute__((address_space(1))) unsigned int*)g,
      (__attribute__((address_space(3))) unsigned int*)l, 16, 0, 0);
}

__device__ __forceinline__ u32 cvt_pk_bf16(float lo, float hi) {
  u32 r;
  asm("v_cvt_pk_bf16_f32 %0, %1, %2" : "=v"(r) : "v"(lo), "v"(hi));
  return r;
}
// v_permlane32_swap: a' = [a.lo31 | b.lo31], b' = [a.hi31 | b.hi31]
__device__ __forceinline__ void permswap(u32& a, u32& b) {
  asm volatile("v_permlane32_swap_b32 %0, %1" : "+v"(a), "+v"(b));
}

// ---------------------------------------------------------------------------
// Weight transpose to bf16: dst[o][i] = (bf16)src[i][o], 512x512 each.
// ---------------------------------------------------------------------------
__global__ void wtrans_kernel(const float* __restrict__ wq, const float* __restrict__ wk,
                              const float* __restrict__ wv, const float* __restrict__ wo,
                              bf16* __restrict__ wqkvT, bf16* __restrict__ woT) {
  __shared__ float tile[32][33];
  int z = blockIdx.z;
  const float* src = (z == 0) ? wq : (z == 1) ? wk : (z == 2) ? wv : wo;
  bf16* dst = (z < 3) ? (wqkvT + (size_t)z * 512 * 512) : woT;
  int bx = blockIdx.x, by = blockIdx.y;
  int tx = threadIdx.x, ty = threadIdx.y;
#pragma unroll
  for (int yy = 0; yy < 4; ++yy)
    tile[ty + 8 * yy][tx] = src[(size_t)(by * 32 + ty + 8 * yy) * 512 + bx * 32 + tx];
  __syncthreads();
#pragma unroll
  for (int yy = 0; yy < 4; ++yy)
    dst[(size_t)(bx * 32 + ty + 8 * yy) * 512 + by * 32 + tx] = (bf16)tile[tx][ty + 8 * yy];
}

// ---------------------------------------------------------------------------
// LayerNorm + positional embedding -> bf16 h [8192][512]. One row per wave.
// ---------------------------------------------------------------------------
__global__ __launch_bounds__(256) void ln_pe_kernel(const float* __restrict__ x,
                                                    const float* __restrict__ w,
                                                    const float* __restrict__ b,
                                                    const float* __restrict__ pe,
                                                    bf16* __restrict__ h) {
  const int row = blockIdx.x * 4 + (threadIdx.x >> 6);
  const int lane = threadIdx.x & 63;
  const float4* xr = (const float4*)(x + (size_t)row * 512) + lane * 2;
  const float4 a = xr[0], c = xr[1];
  float s = a.x + a.y + a.z + a.w + c.x + c.y + c.z + c.w;
  float ss = a.x * a.x + a.y * a.y + a.z * a.z + a.w * a.w +
             c.x * c.x + c.y * c.y + c.z * c.z + c.w * c.w;
#pragma unroll
  for (int off = 1; off <= 32; off <<= 1) {
    s += __shfl_xor(s, off);
    ss += __shfl_xor(ss, off);
  }
  const float mu = s * (1.0f / 512.0f);
  const float var = ss * (1.0f / 512.0f) - mu * mu;
  const float rs = rsqrtf(var + 1e-5f);
  const float4* wr = (const float4*)w + lane * 2;
  const float4* br = (const float4*)b + lane * 2;
  const float4* pr = (const float4*)(pe + (size_t)(row & 2047) * 512) + lane * 2;
  const float4 w0 = wr[0], w1 = wr[1], b0 = br[0], b1 = br[1], p0 = pr[0], p1 = pr[1];
  bf16x8 o;
  o[0] = (bf16)((a.x - mu) * rs * w0.x + b0.x + p0.x);
  o[1] = (bf16)((a.y - mu) * rs * w0.y + b0.y + p0.y);
  o[2] = (bf16)((a.z - mu) * rs * w0.z + b0.z + p0.z);
  o[3] = (bf16)((a.w - mu) * rs * w0.w + b0.w + p0.w);
  o[4] = (bf16)((c.x - mu) * rs * w1.x + b1.x + p1.x);
  o[5] = (bf16)((c.y - mu) * rs * w1.y + b1.y + p1.y);
  o[6] = (bf16)((c.z - mu) * rs * w1.z + b1.z + p1.z);
  o[7] = (bf16)((c.w - mu) * rs * w1.w + b1.w + p1.w);
  *(bf16x8*)(h + (size_t)row * 512 + lane * 8) = o;
}

// ---------------------------------------------------------------------------
// GEMM mainloop, 2-phase double-buffered: C[128x128] = A[128x512] * Bt[128x512]^T.
// ---------------------------------------------------------------------------
__device__ __forceinline__ void gemm_tile(const bf16* __restrict__ A,
                                          const bf16* __restrict__ Bt,
                                          f32x4 acc[4][4]) {
  __shared__ char lds[32768];  // [2][ A 8KB | B 8KB ]
  const int tid = threadIdx.x, wave = tid >> 6, lane = tid & 63;
  const int wrow = wave >> 1, wcol = wave & 1;
  const int l15 = lane & 15, lg = lane >> 4;
  const char* Ab = (const char*)A + (size_t)blockIdx.x * 128 * 1024;
  const char* Bb = (const char*)Bt + (size_t)blockIdx.y * 128 * 1024;
  const int r0 = wave * 32 + (lane >> 2);
  const int cb = (lane & 3) * 16;
  const size_t so = (size_t)r0 * 1024 + cb;

  const f32x4 z = {0.f, 0.f, 0.f, 0.f};
#pragma unroll
  for (int mi = 0; mi < 4; ++mi)
#pragma unroll
    for (int ni = 0; ni < 4; ++ni) acc[mi][ni] = z;

  {
    char* nb = lds;
    gload16(Ab + so, nb + wave * 2048);
    gload16(Ab + so + 16 * 1024, nb + wave * 2048 + 1024);
    gload16(Bb + so, nb + 8192 + wave * 2048);
    gload16(Bb + so + 16 * 1024, nb + 8192 + wave * 2048 + 1024);
  }
  __syncthreads();

  for (int kt = 0; kt < 16; ++kt) {
    if (kt < 15) {
      char* nb = lds + ((kt + 1) & 1) * 16384;
      const char* As = Ab + so + (kt + 1) * 64;
      const char* Bs = Bb + so + (kt + 1) * 64;
      gload16(As, nb + wave * 2048);
      gload16(As + 16 * 1024, nb + wave * 2048 + 1024);
      gload16(Bs, nb + 8192 + wave * 2048);
      gload16(Bs + 16 * 1024, nb + 8192 + wave * 2048 + 1024);
    }
    char* lA = lds + (kt & 1) * 16384;
    char* lB = lA + 8192;
    bf16x8 av[4], bv[4];
#pragma unroll
    for (int mi = 0; mi < 4; ++mi)
      av[mi] = *(const bf16x8*)(lA + (wrow * 64 + mi * 16 + l15) * 64 + lg * 16);
#pragma unroll
    for (int ni = 0; ni < 4; ++ni)
      bv[ni] = *(const bf16x8*)(lB + (wcol * 64 + ni * 16 + l15) * 64 + lg * 16);
    __builtin_amdgcn_s_setprio(1);
#pragma unroll
    for (int mi = 0; mi < 4; ++mi)
#pragma unroll
      for (int ni = 0; ni < 4; ++ni)
        acc[mi][ni] = MFMA16(av[mi], bv[ni], acc[mi][ni]);
    __builtin_amdgcn_s_setprio(0);
    __syncthreads();
  }
}

// ---------------------------------------------------------------------------
// QKV projection. q pre-scaled by 1/8 * log2(e) (softmax done in log2 space).
// ---------------------------------------------------------------------------
__global__ __launch_bounds__(256, 3) void gemm_qkv_kernel(
    const bf16* __restrict__ h, const bf16* __restrict__ wqkvT,
    const float* __restrict__ bvec, bf16* __restrict__ qo, bf16* __restrict__ ko,
    bf16* __restrict__ vo) {
  f32x4 acc[4][4];
  gemm_tile(h, wqkvT, acc);
  const int tid = threadIdx.x, wave = tid >> 6, lane = tid & 63;
  const int wrow = wave >> 1, wcol = wave & 1;
  const int l15 = lane & 15, lg = lane >> 4;
  const int row0 = blockIdx.x * 128 + wrow * 64;
  const int col0 = blockIdx.y * 128 + wcol * 64;
#pragma unroll
  for (int mi = 0; mi < 4; ++mi) {
#pragma unroll
    for (int ni = 0; ni < 4; ++ni) {
      int c = col0 + ni * 16 + l15;
      int proj = c >> 9;
      int wc = c & 511;
      int head = wc >> 6, d = wc & 63;
      int rb = row0 + mi * 16 + lg * 4;
      int bb = rb >> 11, n = rb & 2047;
      if (proj == 2) {
        float bias = bvec[wc];
        bf16x4 pv;
#pragma unroll
        for (int reg = 0; reg < 4; ++reg) pv[reg] = (bf16)(acc[mi][ni][reg] + bias);
        *(bf16x4*)(vo + ((size_t)(bb * 8 + head) * 64 + d) * 2048 + n) = pv;
      } else if (proj == 0) {
#pragma unroll
        for (int reg = 0; reg < 4; ++reg)
          qo[((size_t)(bb * 8 + head) * 2048 + (n + reg)) * 64 + d] =
              (bf16)(acc[mi][ni][reg] * (0.125f * 1.44269504f));
      } else {
#pragma unroll
        for (int reg = 0; reg < 4; ++reg)
          ko[((size_t)(bb * 8 + head) * 2048 + (n + reg)) * 64 + d] =
              (bf16)acc[mi][ni][reg];
      }
    }
  }
}

// ---------------------------------------------------------------------------
// Flash attention, 32x32x16 MFMA, swapped QK^T, in-register P.
// 512 blocks XCD-pinned (4 bh x 512KB KV = 2MB per XCD L2).
// 4 waves x 32 q-rows = 128 q-rows/block. KV tiles of 128 keys, double-buffered
// global_load_lds (pre-swizzled src); ONE barrier per tile (16 tiles).
// S^T = mfma(K,Q): lane owns q = lane&31 in BOTH S^T (col) and PV-A (row) ->
// P redistribution = 8 cvt_pk + 4 permlane32_swap per 32-key tile, no LDS.
// ---------------------------------------------------------------------------
__global__ __launch_bounds__(256, 2) void attn_kernel(const bf16* __restrict__ q,
                                                      const bf16* __restrict__ k,
                                                      const bf16* __restrict__ v,
                                                      bf16* __restrict__ ao) {
  __shared__ char lds[65536];  // [2][ K 16KB | V 16KB ]
  const int tid = threadIdx.x, wave = tid >> 6, lane = tid & 63;
  const int l31 = lane & 31, hi = lane >> 5;

  const int bid = blockIdx.x;
  const int xcd = bid & 7, slot = bid >> 3;      // 512 blocks
  const int bh = xcd + 8 * (slot >> 4);          // 4 bh-groups per XCD
  const int qt = slot & 15;                      // 16 q-tiles of 128 rows
  const int bb = bh >> 3, hh = bh & 7;

  const char* ksrc = (const char*)(k + (size_t)bh * 2048 * 64);   // rowstride 128B
  const char* vsrc = (const char*)(v + (size_t)bh * 64 * 2048);   // rowstride 4096B

  // staging geometry (linear LDS dest, inverse-swizzled global src)
  const int krow0 = wave * 32 + (lane >> 3);  // + i*8 ; K rows of 128B
  const int kcolb = (lane & 7) * 16;
  const int vrow0 = wave * 16 + (lane >> 4);  // + i*4 ; V rows of 256B
  const int vcolb = (lane & 15) * 16;

  // Q fragments (B-operand): col=q=lane&31, k=hi*8+j ; pre-scaled by 0.125*log2e
  const int q0 = qt * 128 + wave * 32;
  const bf16* qbase = q + ((size_t)bh * 2048 + q0) * 64;
  bf16x8 qf[4];
#pragma unroll
  for (int ks = 0; ks < 4; ++ks)
    qf[ks] = *(const bf16x8*)(qbase + l31 * 64 + ks * 16 + hi * 8);

  f32x16 oacc[2] = {};
  float mrun = -1e30f, lrun = 0.f;

#define STAGE(T, BUF)                                                          \
  {                                                                            \
    char* Kd = (BUF);                                                          \
    char* Vd = (BUF) + 16384;                                                  \
    const char* kg = ksrc + (size_t)(T) * 16384;                               \
    const char* vg = vsrc + (size_t)(T) * 256;                                 \
    _Pragma("unroll") for (int i = 0; i < 4; ++i) {                            \
      int r = krow0 + i * 8;                                                   \
      gload16(kg + (size_t)r * 128 + (kcolb ^ ((r & 7) << 4)),                 \
              Kd + (wave * 32 + i * 8) * 128);                                 \
      int rv = vrow0 + i * 4;                                                  \
      gload16(vg + (size_t)rv * 4096 + (vcolb ^ ((rv & 15) << 4)),             \
              Vd + (wave * 16 + i * 4) * 256);                                 \
    }                                                                          \
  }

  STAGE(0, lds);
  __syncthreads();

  for (int t = 0; t < 16; ++t) {
    if (t + 1 < 16) STAGE(t + 1, lds + ((t + 1) & 1) * 32768);
    char* Ksh = lds + (t & 1) * 32768;
    char* Vsh = Ksh + 16384;

#pragma unroll
    for (int sub = 0; sub < 2; ++sub) {
      // ---- S^T = K x Q over 64 keys (2 x 32-key tiles) ----
      f32x16 sacc[2] = {};
      __builtin_amdgcn_s_setprio(1);
#pragma unroll
      for (int kt = 0; kt < 2; ++kt) {
        const int row = sub * 64 + kt * 32 + l31;
        const int swz = (row & 7) << 4;
#pragma unroll
        for (int ks = 0; ks < 4; ++ks) {
          bf16x8 kf = *(const bf16x8*)(Ksh + row * 128 + ((ks * 32 + hi * 16) ^ swz));
          sacc[kt] = MFMA32(kf, qf[ks], sacc[kt]);
        }
      }
      __builtin_amdgcn_s_setprio(0);

      // ---- online softmax (log2 space); lane owns q = lane&31 ----
      float mt = sacc[0][0];
#pragma unroll
      for (int kt = 0; kt < 2; ++kt)
#pragma unroll
        for (int reg = 0; reg < 16; ++reg) mt = fmaxf(mt, sacc[kt][reg]);
      mt = fmaxf(mt, __shfl_xor(mt, 32));
      if (__any(mt > mrun + 11.5f)) {  // defer-max: rescale only on big growth
        float mn = fmaxf(mrun, mt);
        float sc = EXP2(mrun - mn);
        mrun = mn;
        lrun *= sc;
#pragma unroll
        for (int reg = 0; reg < 16; ++reg) {
          float s2 = __shfl(sc, (reg & 3) + 8 * (reg >> 2) + 4 * hi);
          oacc[0][reg] *= s2;
          oacc[1][reg] *= s2;
        }
      }
      float rs = 0.f;
      u32 c[2][8];
#pragma unroll
      for (int kt = 0; kt < 2; ++kt)
#pragma unroll
        for (int gp = 0; gp < 4; ++gp) {
          float p0 = EXP2(sacc[kt][gp * 4 + 0] - mrun);
          float p1 = EXP2(sacc[kt][gp * 4 + 1] - mrun);
          float p2 = EXP2(sacc[kt][gp * 4 + 2] - mrun);
          float p3 = EXP2(sacc[kt][gp * 4 + 3] - mrun);
          rs += (p0 + p1) + (p2 + p3);
          c[kt][gp * 2 + 0] = cvt_pk_bf16(p0, p1);
          c[kt][gp * 2 + 1] = cvt_pk_bf16(p2, p3);
        }
      lrun += rs;  // per-half partial; combined in epilogue

      // ---- P -> A-operand frags, in-register (half-swap) ----
      bf16x8 pf[4];
#pragma unroll
      for (int kt = 0; kt < 2; ++kt)
#pragma unroll
        for (int mm = 0; mm < 2; ++mm) {
          u32 a0 = c[kt][mm * 4 + 0], b0 = c[kt][mm * 4 + 2];
          u32 a1 = c[kt][mm * 4 + 1], b1 = c[kt][mm * 4 + 3];
          permswap(a0, b0);
          permswap(a1, b1);
          union { u32x4 w; bf16x8 v; } u;
          u.w = (u32x4){a0, a1, b0, b1};
          pf[kt * 2 + mm] = u.v;
        }

      // ---- PV: O[q][d] += P[q][key] x V^T[d][key] ----
      __builtin_amdgcn_s_setprio(1);
#pragma unroll
      for (int dt = 0; dt < 2; ++dt) {
        const int row = dt * 32 + l31;
        const int swz = (row & 15) << 4;
#pragma unroll
        for (int m = 0; m < 4; ++m) {
          bf16x8 vf = *(const bf16x8*)(Vsh + row * 256 +
                                       ((sub * 128 + m * 32 + hi * 16) ^ swz));
          oacc[dt] = MFMA32(pf[m], vf, oacc[dt]);
        }
      }
      __builtin_amdgcn_s_setprio(0);
    }
    __syncthreads();  // drains t+1 staging; all waves done with buf t
  }
#undef STAGE

  // epilogue: combine half-sums, normalize, write ao[b][n][hh*64+d]
  lrun += __shfl_xor(lrun, 32);
#if __has_builtin(__builtin_amdgcn_rcpf)
  float rin = __builtin_amdgcn_rcpf(lrun);
#else
  float rin = 1.0f / lrun;
#endif
#pragma unroll
  for (int reg = 0; reg < 16; ++reg) {
    int qrow = (reg & 3) + 8 * (reg >> 2) + 4 * hi;
    float rr = __shfl(rin, qrow);
    size_t base = ((size_t)bb * 2048 + q0 + qrow) * 512 + hh * 64;
    ao[base + l31] = (bf16)(oacc[0][reg] * rr);
    ao[base + 32 + l31] = (bf16)(oacc[1][reg] * rr);
  }
}

// ---------------------------------------------------------------------------
// Output projection + bias + residual.
// ---------------------------------------------------------------------------
__global__ __launch_bounds__(256, 3) void gemm_out_kernel(
    const bf16* __restrict__ ao, const bf16* __restrict__ woT,
    const float* __restrict__ bo, const float* __restrict__ x,
    float* __restrict__ out) {
  f32x4 acc[4][4];
  gemm_tile(ao, woT, acc);
  const int tid = threadIdx.x, wave = tid >> 6, lane = tid & 63;
  const int wrow = wave >> 1, wcol = wave & 1;
  const int l15 = lane & 15, lg = lane >> 4;
  const int row0 = blockIdx.x * 128 + wrow * 64;
  const int col0 = blockIdx.y * 128 + wcol * 64;
#pragma unroll
  for (int mi = 0; mi < 4; ++mi) {
#pragma unroll
    for (int ni = 0; ni < 4; ++ni) {
      int c = col0 + ni * 16 + l15;
      float bias = bo[c];
#pragma unroll
      for (int reg = 0; reg < 4; ++reg) {
        int r = row0 + mi * 16 + lg * 4 + reg;
        size_t ofs = (size_t)r * 512 + c;
        out[ofs] = acc[mi][ni][reg] + bias + x[ofs];
      }
    }
  }
}

// ---------------------------------------------------------------------------
extern "C" void kernel_launch(void* const* d_in, const int* in_sizes, int n_in,
                              void* d_out, int out_size, void* d_ws, size_t ws_size,
                              hipStream_t stream) {
  const float* x   = (const float*)d_in[0];
  const float* lnw = (const float*)d_in[1];
  const float* lnb = (const float*)d_in[2];
  const float* wq  = (const float*)d_in[3];
  const float* wk  = (const float*)d_in[4];
  const float* wv  = (const float*)d_in[5];
  const float* bv  = (const float*)d_in[6];
  const float* wo  = (const float*)d_in[7];
  const float* bo  = (const float*)d_in[8];
  const float* pe  = (const float*)d_in[9];
  float* out = (float*)d_out;

  char* ws = (char*)d_ws;
  bf16* hbuf  = (bf16*)(ws);               // [8192][512] h, reused as attn-out
  bf16* wqkvT = (bf16*)(ws + 8388608);     // [1536][512]
  bf16* woT   = (bf16*)(ws + 9961472);     // [512][512]
  bf16* qb    = (bf16*)(ws + 10485760);    // [32][2048][64] (pre-scaled)
  bf16* kb    = (bf16*)(ws + 18874368);    // [32][2048][64]
  bf16* vb    = (bf16*)(ws + 27262976);    // [32][64][2048] (transposed)
  bf16* aob   = hbuf;

  hipLaunchKernelGGL(wtrans_kernel, dim3(16, 16, 4), dim3(32, 8), 0, stream,
                     wq, wk, wv, wo, wqkvT, woT);
  hipLaunchKernelGGL(ln_pe_kernel, dim3(2048), dim3(256), 0, stream,
                     x, lnw, lnb, pe, hbuf);
  hipLaunchKernelGGL(gemm_qkv_kernel, dim3(64, 12), dim3(256), 0, stream,
                     hbuf, wqkvT, bv, qb, kb, vb);
  hipLaunchKernelGGL(attn_kernel, dim3(512), dim3(256), 0, stream,
                     qb, kb, vb, aob);
  hipLaunchKernelGGL(gemm_out_kernel, dim3(64, 4), dim3(256), 0, stream,
                     aob, woT, bo, x, out);
}